// Round 1
// 772.847 us; speedup vs baseline: 1.0225x; 1.0225x over previous
//
#include <hip/hip_runtime.h>
#include <hip/hip_bf16.h>
#include <stdint.h>

// R7: scores stored as bf16(exp(masked v)) in the S1/S2 M_MASK epilogues
// (masked -> exact 0). The two PV GEMMs drop the AEXP A-path entirely and
// become plain global_load_lds GEMMs (no 32x __expf + f2bf + reg->LDS repack
// per thread per K-step, no double-exp across the two D-tiles). rsum moves
// to an S1-epilogue row-sum (shfl over l15 + atomicAdd per wave partial).

#define B_ 8
#define N_ 4096
#define E_ 2048
#define D_ 256
#define INF_SUB (-9.0e15f)

typedef short bf16x8 __attribute__((ext_vector_type(8)));
typedef float f32x4 __attribute__((ext_vector_type(4)));
typedef unsigned short us8 __attribute__((ext_vector_type(8)));

#define AS1 __attribute__((address_space(1)))
#define AS3 __attribute__((address_space(3)))

__device__ __forceinline__ unsigned short f2bf(float f) {
    union { float f; unsigned int u; } v; v.f = f;
    unsigned int r = v.u + 0x7fffu + ((v.u >> 16) & 1u);
    return (unsigned short)(r >> 16);
}
__device__ __forceinline__ float bf2f(unsigned short h) {
    union { unsigned int u; float f; } v; v.u = ((unsigned int)h) << 16;
    return v.f;
}
__device__ __forceinline__ float waveReduceSum(float v) {
#pragma unroll
    for (int o = 32; o > 0; o >>= 1) v += __shfl_xor(v, o, 64);
    return v;
}

// ---------------- LayerNorm over D=256 -> bf16 ------------------------------
__global__ __launch_bounds__(256) void ln_kernel(const float* __restrict__ x,
                                                 const float* __restrict__ gamma,
                                                 const float* __restrict__ beta,
                                                 unsigned short* __restrict__ yb) {
    __shared__ float red[8];
    const int row = blockIdx.x;
    const int t = threadIdx.x;
    const int lane = t & 63, wid = t >> 6;
    const float v = x[(size_t)row * D_ + t];
    float s = waveReduceSum(v);
    if (lane == 0) red[wid] = s;
    __syncthreads();
    const float mu = (red[0] + red[1] + red[2] + red[3]) * (1.0f / D_);
    const float d = v - mu;
    float s2 = waveReduceSum(d * d);
    if (lane == 0) red[4 + wid] = s2;
    __syncthreads();
    const float var = (red[4] + red[5] + red[6] + red[7]) * (1.0f / D_);
    yb[(size_t)row * D_ + t] = f2bf(gamma[t] * d * rsqrtf(var + 1e-5f) + beta[t]);
}

// ---------------- pack ht -> bitmask: bits[b][e][n>>5] bit (n&31) -----------
__global__ __launch_bounds__(256) void pack_mask(const int* __restrict__ ht,
                                                 uint32_t* __restrict__ bits) {
    const int row = blockIdx.x;
    const int t = threadIdx.x, wid = t >> 6, lane = t & 63;
    const int* hrow = ht + (size_t)row * N_;
    uint32_t* brow = bits + (size_t)row * (N_ / 32);
#pragma unroll
    for (int i = 0; i < 16; ++i) {
        const int c = wid * 16 + i;
        const int v = hrow[c * 64 + lane];
        unsigned long long m = __ballot(v > 0);
        if (lane == 0) {
            brow[c * 2] = (uint32_t)m;
            brow[c * 2 + 1] = (uint32_t)(m >> 32);
        }
    }
}

// ---------------- fp32 [N,D] -> bf16 [N,D] + bf16 [D,N] ---------------------
__global__ __launch_bounds__(256) void prep_hidden(const float* __restrict__ in,
                                                   unsigned short* __restrict__ hb,
                                                   unsigned short* __restrict__ hT) {
    __shared__ unsigned short tile[64][65];
    const int b = blockIdx.z;
    in += (size_t)b * N_ * D_;
    hb += (size_t)b * N_ * D_;
    hT += (size_t)b * D_ * N_;
    const int n0 = blockIdx.y * 64, d0 = blockIdx.x * 64;
    const int t = threadIdx.x;
    const int tr = t >> 4, tc = (t & 15) * 4;
#pragma unroll
    for (int q = 0; q < 4; ++q) {
        const int rr = q * 16 + tr;
        const float4 f = *(const float4*)&in[(size_t)(n0 + rr) * D_ + d0 + tc];
        unsigned short h0 = f2bf(f.x), h1 = f2bf(f.y), h2 = f2bf(f.z), h3 = f2bf(f.w);
        *(ushort4*)&hb[(size_t)(n0 + rr) * D_ + d0 + tc] = make_ushort4(h0, h1, h2, h3);
        tile[rr][tc + 0] = h0; tile[rr][tc + 1] = h1;
        tile[rr][tc + 2] = h2; tile[rr][tc + 3] = h3;
    }
    __syncthreads();
#pragma unroll
    for (int q = 0; q < 4; ++q) {
        const int cc = q * 16 + tr;
        ushort4 o = make_ushort4(tile[tc + 0][cc], tile[tc + 1][cc],
                                 tile[tc + 2][cc], tile[tc + 3][cc]);
        *(ushort4*)&hT[(size_t)(d0 + cc) * N_ + n0 + tc] = o;
    }
}

// ---------------- tiny: w[D,D] f32 -> wT[D,D] bf16 --------------------------
__global__ __launch_bounds__(256) void cast_wT(const float* __restrict__ w,
                                               unsigned short* __restrict__ wT) {
    const int gid = blockIdx.x * 256 + threadIdx.x;
    const int i = gid >> 8, j = gid & 255;
    wT[j * D_ + i] = f2bf(w[i * D_ + j]);
}

// ---- PV slab reduce: edge_h = (slab0+slab1)/rsum + eln; also f32 [D,E] T ---
__global__ __launch_bounds__(256) void reduce_pv(const float* __restrict__ slab,
                                                 const unsigned short* __restrict__ eln,
                                                 const float* __restrict__ rsum,
                                                 unsigned short* __restrict__ eh,
                                                 float* __restrict__ ehT) {
    __shared__ float tile[64][65];
    const int b = blockIdx.z;
    const float* s0 = slab + (size_t)(b * 2) * E_ * D_;
    const float* s1 = slab + (size_t)(b * 2 + 1) * E_ * D_;
    const int e0 = blockIdx.y * 64, d0 = blockIdx.x * 64;
    const int t = threadIdx.x;
    const int tr = t >> 4, tc = (t & 15) * 4;
#pragma unroll
    for (int q = 0; q < 4; ++q) {
        const int rr = q * 16 + tr;
        const int row = e0 + rr;
        const float4 v0 = *(const float4*)&s0[(size_t)row * D_ + d0 + tc];
        const float4 v1 = *(const float4*)&s1[(size_t)row * D_ + d0 + tc];
        const float inv = 1.0f / rsum[(size_t)b * E_ + row];
        const ushort4 el = *(const ushort4*)&eln[(size_t)b * E_ * D_ + (size_t)row * D_ + d0 + tc];
        const float x0 = (v0.x + v1.x) * inv + bf2f(el.x);
        const float x1 = (v0.y + v1.y) * inv + bf2f(el.y);
        const float x2 = (v0.z + v1.z) * inv + bf2f(el.z);
        const float x3 = (v0.w + v1.w) * inv + bf2f(el.w);
        *(ushort4*)&eh[(size_t)b * E_ * D_ + (size_t)row * D_ + d0 + tc] =
            make_ushort4(f2bf(x0), f2bf(x1), f2bf(x2), f2bf(x3));
        tile[rr][tc + 0] = x0; tile[rr][tc + 1] = x1;
        tile[rr][tc + 2] = x2; tile[rr][tc + 3] = x3;
    }
    __syncthreads();
#pragma unroll
    for (int q = 0; q < 4; ++q) {
        const int cc = q * 16 + tr;
        float4 o = make_float4(tile[tc + 0][cc], tile[tc + 1][cc],
                               tile[tc + 2][cc], tile[tc + 3][cc]);
        *(float4*)&ehT[(size_t)b * D_ * E_ + (size_t)(d0 + cc) * E_ + e0 + tc] = o;
    }
}

// ---- edge_hsT[d,e] = ehT[d,e] / lsum[e]  (f32 in, bf16 out, [B,D,E]) -------
__global__ __launch_bounds__(256) void scale_ehT(const float* __restrict__ ehT,
                                                 const float* __restrict__ lsum,
                                                 unsigned short* __restrict__ ehs) {
    const size_t base = ((size_t)blockIdx.x * 256 + threadIdx.x) * 8;
    const int b = (int)(base / ((size_t)D_ * E_));
    const int e = (int)(base % E_);
    const float4 f0 = *(const float4*)&ehT[base];
    const float4 f1 = *(const float4*)&ehT[base + 4];
    const float4 l0 = *(const float4*)&lsum[(size_t)b * E_ + e];
    const float4 l1 = *(const float4*)&lsum[(size_t)b * E_ + e + 4];
    us8 o;
    o[0] = f2bf(f0.x / l0.x); o[1] = f2bf(f0.y / l0.y);
    o[2] = f2bf(f0.z / l0.z); o[3] = f2bf(f0.w / l0.w);
    o[4] = f2bf(f1.x / l1.x); o[5] = f2bf(f1.y / l1.y);
    o[6] = f2bf(f1.z / l1.z); o[7] = f2bf(f1.w / l1.w);
    *(us8*)&ehs[base] = o;
}

// ---------------- MFMA NT GEMM: C[m,n] = sum_k A[m,k]*Bt[n,k] ---------------
// 128x128 tile, BK=64, global_load_lds w=16, chunk-rotate swizzle mod 8.
// M_MASK now stores bf16(exp(masked v)) (masked -> 0.0). RSUM: row exp-sums
// into sums[] (stage-1 rsum). CSUM: column exp-sums (stage-2 lsum).
#define M_BF16 0
#define M_MASK 1
#define M_F32 2

template <int MODE, int MASKOR, int RSUM, int SPLIT, int CSUM>
__global__ __launch_bounds__(256) void mfma_gemm_nt(
        const short* __restrict__ A, const short* __restrict__ Bm,
        void* __restrict__ Cv, const uint32_t* __restrict__ bits,
        float* __restrict__ sums,
        int K, int ldc, size_t sA, size_t sB, size_t sC, float scale) {
    __shared__ __align__(16) short ls[(MODE == M_F32) ? 16384 : 16896];
    __shared__ uint32_t mwords[MASKOR ? 512 : 4];
    short* lsA = ls;              // 128 x 64 bf16 = 16 KB
    short* lsB = ls + 8192;       // 128 x 64 bf16 = 16 KB
    const int zb = blockIdx.z;
    const int b = SPLIT ? (zb >> 1) : zb;
    A += (size_t)b * sA;
    Bm += (size_t)b * sB;
    const int m0 = blockIdx.y * 128, n0 = blockIdx.x * 128;
    const int tid = threadIdx.x, wid = tid >> 6, lane = tid & 63;
    const int l15 = lane & 15, kg = lane >> 4;
    const int wr = wid >> 1, wc = wid & 1;

    if (MASKOR) {
        const uint32_t* bb = bits + (size_t)b * E_ * (N_ / 32);
#pragma unroll
        for (int q = 0; q < 2; ++q) {
            const int idx = q * 256 + tid;
            mwords[idx] = (MASKOR == 1)
                ? bb[(size_t)(m0 + (idx >> 2)) * (N_ / 32) + (n0 >> 5) + (idx & 3)]
                : bb[(size_t)(n0 + (idx >> 2)) * (N_ / 32) + (m0 >> 5) + (idx & 3)];
        }
    }

    // fragment LDS addressing: row r, k-chunk ck (8 shorts) stored at position
    // p = (ck + (r>>1)) & 7 within the 64-short row.
    int raoff[4], rota[4], rboff[4], rotb[4];
#pragma unroll
    for (int i = 0; i < 4; ++i) {
        const int ra = wr * 64 + i * 16 + l15;
        raoff[i] = ra * 64; rota[i] = kg + (ra >> 1);
        const int rb = wc * 64 + i * 16 + l15;
        rboff[i] = rb * 64; rotb[i] = kg + (rb >> 1);
    }
    const f32x4 zero = {0.f, 0.f, 0.f, 0.f};
    f32x4 acc[4][4];
#pragma unroll
    for (int i = 0; i < 4; ++i)
#pragma unroll
        for (int j = 0; j < 4; ++j) acc[i][j] = zero;

    const int kt0 = SPLIT ? (zb & 1) * (K >> 1) : 0;
    const int ktE = SPLIT ? kt0 + (K >> 1) : K;
    for (int kt = kt0; kt < ktE; kt += 64) {
        __syncthreads();
#pragma unroll
        for (int q = 0; q < 4; ++q) {
            const int c = q * 256 + tid;
            const int r = c >> 3;
            const int kc = ((c & 7) - (r >> 1)) & 7;
            const short* ga = A + (size_t)(m0 + r) * K + kt + kc * 8;
            __builtin_amdgcn_global_load_lds((const AS1 void*)ga,
                (AS3 void*)(lsA + (q * 256 + wid * 64) * 8), 16, 0, 0);
            const short* gb = Bm + (size_t)(n0 + r) * K + kt + kc * 8;
            __builtin_amdgcn_global_load_lds((const AS1 void*)gb,
                (AS3 void*)(lsB + (q * 256 + wid * 64) * 8), 16, 0, 0);
        }
        __syncthreads();
#pragma unroll
        for (int s = 0; s < 2; ++s) {
            bf16x8 fa[4], fb[4];
#pragma unroll
            for (int i = 0; i < 4; ++i)
                fa[i] = *(const bf16x8*)(lsA + raoff[i] + (((s * 4 + rota[i]) & 7) << 3));
#pragma unroll
            for (int j = 0; j < 4; ++j)
                fb[j] = *(const bf16x8*)(lsB + rboff[j] + (((s * 4 + rotb[j]) & 7) << 3));
#pragma unroll
            for (int i = 0; i < 4; ++i)
#pragma unroll
                for (int j = 0; j < 4; ++j)
                    acc[i][j] = __builtin_amdgcn_mfma_f32_16x16x32_bf16(fa[i], fb[j], acc[i][j], 0, 0, 0);
        }
    }

    __syncthreads();  // fragment reads done; ls free for repack

    if (MODE == M_F32) {
        float* C = (float*)Cv + (SPLIT ? (size_t)zb * sC : (size_t)b * sC);
        float* lsF = (float*)ls;
#pragma unroll
        for (int h = 0; h < 4; ++h) {
            if (wr == (h >> 1)) {
#pragma unroll
                for (int ii = 0; ii < 2; ++ii) {
                    const int i = (h & 1) * 2 + ii;
#pragma unroll
                    for (int j = 0; j < 4; ++j)
#pragma unroll
                        for (int r = 0; r < 4; ++r) {
                            const int rl = ii * 16 + kg * 4 + r;
                            const int cl = wc * 64 + j * 16 + l15;
                            lsF[rl * 128 + cl] = acc[i][j][r];
                        }
                }
            }
            __syncthreads();
#pragma unroll
            for (int si = 0; si < 4; ++si) {
                const int row = (tid >> 5) + si * 8;
                const int colb = (tid & 31) * 4;
                float4 v = *(float4*)&lsF[row * 128 + colb];
                *(float4*)&C[(size_t)(m0 + h * 32 + row) * ldc + n0 + colb] = v;
            }
            __syncthreads();
        }
    } else {
        // single-phase bf16 repack, stride 132 (conflict-free), all waves active
        unsigned short* C = (unsigned short*)Cv + (size_t)b * sC;
        float evsum[4] = {0.f, 0.f, 0.f, 0.f};
#pragma unroll
        for (int i = 0; i < 4; ++i) {
#pragma unroll
            for (int r = 0; r < 4; ++r) {
                const int rowfull = wr * 64 + i * 16 + kg * 4 + r;
                uint64_t mwr = 0;
                if (MODE == M_MASK && MASKOR == 1)
                    mwr = *(const uint64_t*)&mwords[rowfull * 4 + wc * 2];
                float rs = 0.f;
#pragma unroll
                for (int j = 0; j < 4; ++j) {
                    const int cl = wc * 64 + j * 16 + l15;
                    float v = acc[i][j][r];
                    if (MODE == M_MASK) {
                        v *= scale;
                        uint32_t bit;
                        if (MASKOR == 1) {
                            bit = (uint32_t)(mwr >> (j * 16 + l15)) & 1u;
                        } else {
                            const uint64_t mwc = *(const uint64_t*)&mwords[cl * 4 + wr * 2];
                            bit = (uint32_t)(mwc >> (i * 16 + kg * 4 + r)) & 1u;
                        }
                        v = bit ? __expf(v) : 0.f;  // store exp'd score
                        if (CSUM) evsum[j] += v;
                        if (RSUM) rs += v;
                    }
                    ls[rowfull * 132 + cl] = (short)f2bf(v);
                }
                if (RSUM) {
                    // sum across l15 (16 lanes of the same kg = same row)
                    rs += __shfl_xor(rs, 1, 64);
                    rs += __shfl_xor(rs, 2, 64);
                    rs += __shfl_xor(rs, 4, 64);
                    rs += __shfl_xor(rs, 8, 64);
                    if (l15 == 0)
                        atomicAdd(&sums[(size_t)b * E_ + m0 + rowfull], rs);
                }
            }
        }
        __syncthreads();
#pragma unroll
        for (int si = 0; si < 8; ++si) {
            const int row = (tid >> 4) + si * 16;
            const int col = (tid & 15) * 8;
            us8 val = *(us8*)&ls[row * 132 + col];
            *(us8*)&C[(size_t)(m0 + row) * ldc + n0 + col] = val;
        }
        if (CSUM) {
#pragma unroll
            for (int j = 0; j < 4; ++j) {
                float cs = evsum[j];
                cs += __shfl_xor(cs, 16, 64);
                cs += __shfl_xor(cs, 32, 64);
                if (kg == 0)
                    atomicAdd(&sums[(size_t)b * E_ + n0 + wc * 64 + j * 16 + l15], cs);
            }
        }
    }
}

// ---------------------------------------------------------------------------
extern "C" void kernel_launch(void* const* d_in, const int* in_sizes, int n_in,
                              void* d_out, int out_size, void* d_ws, size_t ws_size,
                              hipStream_t stream) {
    const float* hidden = (const float*)d_in[0];    // [B,N,D]
    const int* ht = (const int*)d_in[1];            // [B,E,N]
    const float* edge_emb = (const float*)d_in[2];  // [B,E,D]
    const float* wnk = (const float*)d_in[3];       // [D,D]
    const float* wek = (const float*)d_in[4];       // [D,D]
    const float* gamma = (const float*)d_in[5];     // [D]
    const float* beta = (const float*)d_in[6];      // [D]
    float* out = (float*)d_out;                     // [B,N,D]
    (void)in_sizes; (void)n_in; (void)out_size; (void)ws_size;

    char* w = (char*)d_ws;
    unsigned short* SP = (unsigned short*)w;         w += (size_t)B_ * E_ * N_ * 2;   // 134MB (S1 exp [E,N], then S2T exp [N,E])
    unsigned short* hidden_bf = (unsigned short*)w;  w += (size_t)B_ * N_ * D_ * 2;
    unsigned short* hiddenT_bf = (unsigned short*)w; w += (size_t)B_ * D_ * N_ * 2;
    unsigned short* node_k_bf = (unsigned short*)w;  w += (size_t)B_ * N_ * D_ * 2;
    unsigned short* eln_bf = (unsigned short*)w;     w += (size_t)B_ * E_ * D_ * 2;
    unsigned short* edge_h_bf = (unsigned short*)w;  w += (size_t)B_ * E_ * D_ * 2;
    float* ehT_f32 = (float*)w;                      w += (size_t)B_ * D_ * E_ * 4;
    unsigned short* ehsT_bf = (unsigned short*)w;    w += (size_t)B_ * D_ * E_ * 2;
    unsigned short* edge_k_bf = (unsigned short*)w;  w += (size_t)B_ * E_ * D_ * 2;
    float* slabs = (float*)w;                        w += (size_t)B_ * 2 * E_ * D_ * 4;
    uint32_t* bits = (uint32_t*)w;                   w += (size_t)B_ * E_ * (N_ / 32) * 4;
    float* rsum = (float*)w;                         w += (size_t)B_ * E_ * 4;
    float* lsum = (float*)w;                         w += (size_t)B_ * E_ * 4;
    unsigned short* wnkT = (unsigned short*)w;       w += (size_t)D_ * D_ * 2;
    unsigned short* wekT = (unsigned short*)w;       w += (size_t)D_ * D_ * 2;

    const float scale = 0.0625f;  // 1/sqrt(256)

    // prep
    prep_hidden<<<dim3(D_ / 64, N_ / 64, B_), 256, 0, stream>>>(hidden, hidden_bf, hiddenT_bf);
    cast_wT<<<D_ * D_ / 256, 256, 0, stream>>>(wnk, wnkT);
    cast_wT<<<D_ * D_ / 256, 256, 0, stream>>>(wek, wekT);
    ln_kernel<<<B_ * E_, 256, 0, stream>>>(edge_emb, gamma, beta, eln_bf);
    pack_mask<<<B_ * E_, 256, 0, stream>>>(ht, bits);
    hipMemsetAsync(rsum, 0, (size_t)B_ * E_ * 8, stream);  // rsum + lsum (adjacent)

    // node_k = hidden @ wnk
    mfma_gemm_nt<M_BF16, 0, 0, 0, 0><<<dim3(D_ / 128, (B_ * N_) / 128, 1), 256, 0, stream>>>(
        (const short*)hidden_bf, (const short*)wnkT, node_k_bf, nullptr, nullptr,
        D_, D_, 0, 0, 0, 1.f);
    // S1[e,n] = exp(mask(eln . node_k * scale)); rsum[e] = row exp-sums (RSUM)
    mfma_gemm_nt<M_MASK, 1, 1, 0, 0><<<dim3(N_ / 128, E_ / 128, B_), 256, 0, stream>>>(
        (const short*)eln_bf, (const short*)node_k_bf, SP, bits, rsum,
        D_, N_, (size_t)E_ * D_, (size_t)N_ * D_, (size_t)E_ * N_, scale);
    // PV slabs: slab[b*2+s][e,d] = sum_{n in half s} S1exp[e,n]*hidden[n,d]
    // (plain GEMM now — SP already holds exp'd scores)
    mfma_gemm_nt<M_F32, 0, 0, 1, 0><<<dim3(D_ / 128, E_ / 128, B_ * 2), 256, 0, stream>>>(
        (const short*)SP, (const short*)hiddenT_bf, slabs, nullptr, nullptr,
        N_, D_, (size_t)E_ * N_, (size_t)D_ * N_, (size_t)E_ * D_, 1.f);
    // edge_h = (slab0+slab1)/rsum + eln  -> bf16 [E,D] and f32 [D,E]
    reduce_pv<<<dim3(D_ / 64, E_ / 64, B_), 256, 0, stream>>>(
        slabs, eln_bf, rsum, edge_h_bf, ehT_f32);
    // edge_k = edge_h @ wek
    mfma_gemm_nt<M_BF16, 0, 0, 0, 0><<<dim3(D_ / 128, (B_ * E_) / 128, 1), 256, 0, stream>>>(
        (const short*)edge_h_bf, (const short*)wekT, edge_k_bf, nullptr, nullptr,
        D_, D_, 0, 0, 0, 1.f);
    // S2T[n,e] = exp(mask(node_k . edge_k * scale)); lsum[e] += col exp-sums (CSUM)
    mfma_gemm_nt<M_MASK, 2, 0, 0, 1><<<dim3(E_ / 128, N_ / 128, B_), 256, 0, stream>>>(
        (const short*)node_k_bf, (const short*)edge_k_bf, SP, bits, lsum,
        D_, E_, (size_t)N_ * D_, (size_t)E_ * D_, (size_t)N_ * E_, scale);
    // edge_hs[d,e] = ehT/lsum[e]
    scale_ehT<<<(B_ * D_ * E_) / (256 * 8), 256, 0, stream>>>(ehT_f32, lsum, ehsT_bf);
    // out[n,d] = sum_e S2exp[n,e] * edge_hs[d,e]  (plain GEMM now)
    mfma_gemm_nt<M_F32, 0, 0, 0, 0><<<dim3(D_ / 128, N_ / 128, B_), 256, 0, stream>>>(
        (const short*)SP, (const short*)ehsT_bf, out, nullptr, nullptr,
        E_, D_, (size_t)N_ * E_, (size_t)D_ * E_, (size_t)N_ * D_, 1.f);
}